// Round 1
// baseline (1645.528 us; speedup 1.0000x reference)
//
#include <hip/hip_runtime.h>

#define Bb 64
#define Nn 1152
#define Oo 32
#define DOv 16
#define DIv 8
#define NC 4     // n's per block
#define BPB 16   // b's per block (2 groups of 8)
#define NPART 16 // partial-s copies to spread atomic contention

// Fused routing iteration: recompute x_hat from (w, x), logits = <x_hat, vcum>,
// softmax over o, accumulate c * x_hat into partial s buffers.
// vcum == 0 gives uniform c = 1/32 (iteration 1) automatically.
__global__ __launch_bounds__(256) void caps_route(
    const float* __restrict__ x,     // [B, N, DI]
    const float* __restrict__ w,     // [N, O, DO, DI]
    const float* __restrict__ vcum,  // [B, O, DO]  (sum of previous vj's)
    float* __restrict__ spart)       // [NPART, B, O, DO]
{
    const int t  = threadIdx.x;
    const int o  = t & 31;
    const int bl = t >> 5;            // 0..7
    const int nchunk = blockIdx.x;    // 0..(N/NC-1)
    const int b0 = blockIdx.y * BPB;

    // wlds[r][o] with r = i*8+j; +1 pad -> bank (r+o)%32, conflict-free reads
    __shared__ float wlds[128][33];
    __shared__ float4 xlds4[BPB][2];  // x rows for the 16 b's of this block

    // per-thread vcum fragments for both b-groups (fixed (b,o) per thread)
    float vc0[DOv], vc1[DOv];
#pragma unroll
    for (int i = 0; i < DOv; ++i) vc0[i] = vcum[((size_t)(b0 + bl) * Oo + o) * DOv + i];
#pragma unroll
    for (int i = 0; i < DOv; ++i) vc1[i] = vcum[((size_t)(b0 + 8 + bl) * Oo + o) * DOv + i];

    float sacc0[DOv], sacc1[DOv];
#pragma unroll
    for (int i = 0; i < DOv; ++i) { sacc0[i] = 0.f; sacc1[i] = 0.f; }

    for (int nn = 0; nn < NC; ++nn) {
        const int n = nchunk * NC + nn;

        // stage weight[n] (4096 floats) transposed into wlds
        const float4* wg = reinterpret_cast<const float4*>(w + (size_t)n * (Oo * DOv * DIv));
#pragma unroll
        for (int k = 0; k < 4; ++k) {
            int q = k * 256 + t;          // float4 index 0..1023
            float4 v = wg[q];
            int oo = q >> 5;              // 32 float4's per o
            int r4 = (q & 31) << 2;
            wlds[r4 + 0][oo] = v.x;
            wlds[r4 + 1][oo] = v.y;
            wlds[r4 + 2][oo] = v.z;
            wlds[r4 + 3][oo] = v.w;
        }
        // stage x[b0..b0+15, n, :] (16 rows x 8 floats)
        if (t < 32) {
            int bb = t >> 1, h = t & 1;
            xlds4[bb][h] = reinterpret_cast<const float4*>(
                x + ((size_t)(b0 + bb) * Nn + n) * DIv)[h];
        }
        __syncthreads();

        const float* xs = reinterpret_cast<const float*>(xlds4);
        float xa[DIv], xb[DIv];
#pragma unroll
        for (int j = 0; j < DIv; ++j) { xa[j] = xs[bl * DIv + j]; xb[j] = xs[(8 + bl) * DIv + j]; }

        // x_hat[b, n, o, :] for both b-groups; W element reused twice per LDS read
        float xh0[DOv], xh1[DOv];
#pragma unroll
        for (int i = 0; i < DOv; ++i) { xh0[i] = 0.f; xh1[i] = 0.f; }
#pragma unroll
        for (int i = 0; i < DOv; ++i) {
#pragma unroll
            for (int j = 0; j < DIv; ++j) {
                float wv = wlds[i * DIv + j][o];
                xh0[i] += wv * xa[j];
                xh1[i] += wv * xb[j];
            }
        }

        // logits = <x_hat, vcum>
        float l0 = 0.f, l1 = 0.f;
#pragma unroll
        for (int i = 0; i < DOv; ++i) { l0 += xh0[i] * vc0[i]; l1 += xh1[i] * vc1[i]; }

        // softmax over the 32 o-lanes (xor masks < 32 stay in aligned 32-groups)
        float m0 = l0, m1 = l1;
#pragma unroll
        for (int d = 16; d >= 1; d >>= 1) {
            m0 = fmaxf(m0, __shfl_xor(m0, d));
            m1 = fmaxf(m1, __shfl_xor(m1, d));
        }
        float e0 = __expf(l0 - m0), e1 = __expf(l1 - m1);
        float s0 = e0, s1 = e1;
#pragma unroll
        for (int d = 16; d >= 1; d >>= 1) {
            s0 += __shfl_xor(s0, d);
            s1 += __shfl_xor(s1, d);
        }
        float c0 = e0 / s0, c1 = e1 / s1;

#pragma unroll
        for (int i = 0; i < DOv; ++i) { sacc0[i] += c0 * xh0[i]; sacc1[i] += c1 * xh1[i]; }
        __syncthreads();  // protect wlds before next stage
    }

    // one atomic pass per block (accumulated over NC n's first)
    float* p  = spart + (size_t)(nchunk % NPART) * (Bb * Oo * DOv);
    float* p0 = p + ((size_t)(b0 + bl) * Oo + o) * DOv;
    float* p1 = p + ((size_t)(b0 + 8 + bl) * Oo + o) * DOv;
#pragma unroll
    for (int i = 0; i < DOv; ++i) atomicAdd(p0 + i, sacc0[i]);
#pragma unroll
    for (int i = 0; i < DOv; ++i) atomicAdd(p1 + i, sacc1[i]);
}

// Reduce partials, squash, update vcum (iters 1,2) or write output (iter 3).
__global__ __launch_bounds__(512) void caps_squash(
    const float* __restrict__ spart, float* __restrict__ vcum, float* __restrict__ out)
{
    const int b = blockIdx.x;       // 0..63
    const int t = threadIdx.x;      // o*16 + i
    float s = 0.f;
#pragma unroll
    for (int p = 0; p < NPART; ++p)
        s += spart[(size_t)p * (Bb * Oo * DOv) + (size_t)b * (Oo * DOv) + t];
    float n2 = s * s;
#pragma unroll
    for (int d = 8; d >= 1; d >>= 1) n2 += __shfl_xor(n2, d);  // reduce over Do=16
    float vj = s * (n2 / ((1.f + n2) * sqrtf(n2 + 1e-7f)));
    size_t idx = (size_t)b * (Oo * DOv) + t;
    if (vcum) vcum[idx] += vj;
    if (out)  out[idx] = vj;
}

extern "C" void kernel_launch(void* const* d_in, const int* in_sizes, int n_in,
                              void* d_out, int out_size, void* d_ws, size_t ws_size,
                              hipStream_t stream)
{
    const float* x = (const float*)d_in[0];
    const float* w = (const float*)d_in[1];
    float* out = (float*)d_out;

    float* spart = (float*)d_ws;                              // NPART*B*O*DO floats (2 MB)
    float* vcum  = spart + (size_t)NPART * Bb * Oo * DOv;     // B*O*DO floats (128 KB)

    hipMemsetAsync(vcum, 0, (size_t)Bb * Oo * DOv * sizeof(float), stream);

    dim3 grid(Nn / NC, Bb / BPB);
    dim3 blk(256);

    for (int it = 0; it < 3; ++it) {
        hipMemsetAsync(spart, 0, (size_t)NPART * Bb * Oo * DOv * sizeof(float), stream);
        caps_route<<<grid, blk, 0, stream>>>(x, w, vcum, spart);
        if (it < 2)
            caps_squash<<<dim3(Bb), dim3(Oo * DOv), 0, stream>>>(spart, vcum, nullptr);
        else
            caps_squash<<<dim3(Bb), dim3(Oo * DOv), 0, stream>>>(spart, nullptr, out);
    }
}

// Round 2
// 143.123 us; speedup vs baseline: 11.4973x; 11.4973x over previous
//
#include <hip/hip_runtime.h>

#define Bb 64
#define Nn 1152
#define Oo 32
#define DOv 16
#define DIv 8
#define BPB 16   // b's per block (2 groups of 8)

// One routing iteration, fused: recompute x_hat from (w, x), logits = <x_hat, vcum>,
// softmax over o, accumulate c * x_hat over this block's n-chunk, plain-store the
// partial s. vcum == nullptr means iteration 1 (uniform c = 1/32).
__global__ __launch_bounds__(256) void caps_route(
    const float* __restrict__ x,     // [B, N, DI]
    const float* __restrict__ w,     // [N, O, DO, DI]
    const float* __restrict__ vcum,  // [B, O, DO] or nullptr
    float* __restrict__ spart,       // [nch, B, O, DO]
    int nc)                          // n's per block
{
    const int t  = threadIdx.x;
    const int o  = t & 31;
    const int bl = t >> 5;            // 0..7
    const int n0 = blockIdx.x * nc;
    const int b0 = blockIdx.y * BPB;

    // wlds[r][col] with r = i*8+j, col = o ^ (r>>2)  -> conflict-free reads AND writes
    __shared__ float wlds[128][33];
    __shared__ float4 xlds4[BPB][2];  // x rows for the 16 b's of this block

    const bool have_v = (vcum != nullptr);
    float vc0[DOv], vc1[DOv];
    if (have_v) {
#pragma unroll
        for (int i = 0; i < DOv; ++i) vc0[i] = vcum[((size_t)(b0 + bl) * Oo + o) * DOv + i];
#pragma unroll
        for (int i = 0; i < DOv; ++i) vc1[i] = vcum[((size_t)(b0 + 8 + bl) * Oo + o) * DOv + i];
    }

    float sacc0[DOv], sacc1[DOv];
#pragma unroll
    for (int i = 0; i < DOv; ++i) { sacc0[i] = 0.f; sacc1[i] = 0.f; }

    // prologue: prefetch n0's weight (4 float4/thread) and x rows (lanes t<32)
    float4 wr[4];
    float4 xr;
    {
        const float4* wg = reinterpret_cast<const float4*>(w + (size_t)n0 * (Oo * DOv * DIv));
#pragma unroll
        for (int k = 0; k < 4; ++k) wr[k] = wg[k * 256 + t];
        if (t < 32)
            xr = reinterpret_cast<const float4*>(
                x + ((size_t)(b0 + (t >> 1)) * Nn + n0) * DIv)[t & 1];
    }

    for (int nn = 0; nn < nc; ++nn) {
        // stage current n from registers into LDS (swizzled, conflict-free)
#pragma unroll
        for (int k = 0; k < 4; ++k) {
            int q  = k * 256 + t;         // float4 index 0..1023
            int oo = q >> 5;              // owning o
            int m  = q & 31;              // r>>2 for the 4 elements
            int r4 = m << 2;
            int col = oo ^ m;
            wlds[r4 + 0][col] = wr[k].x;
            wlds[r4 + 1][col] = wr[k].y;
            wlds[r4 + 2][col] = wr[k].z;
            wlds[r4 + 3][col] = wr[k].w;
        }
        if (t < 32) xlds4[t >> 1][t & 1] = xr;
        __syncthreads();

        // prefetch next n while computing current (hides L2/L3 latency)
        if (nn + 1 < nc) {
            int n = n0 + nn + 1;
            const float4* wg = reinterpret_cast<const float4*>(w + (size_t)n * (Oo * DOv * DIv));
#pragma unroll
            for (int k = 0; k < 4; ++k) wr[k] = wg[k * 256 + t];
            if (t < 32)
                xr = reinterpret_cast<const float4*>(
                    x + ((size_t)(b0 + (t >> 1)) * Nn + n) * DIv)[t & 1];
        }

        const float* xs = reinterpret_cast<const float*>(xlds4);
        float xa[DIv], xb[DIv];
#pragma unroll
        for (int j = 0; j < DIv; ++j) { xa[j] = xs[bl * DIv + j]; xb[j] = xs[(8 + bl) * DIv + j]; }

        // x_hat for both b-groups; each LDS read (broadcast to lane pairs) feeds 2 FMAs
        float xh0[DOv], xh1[DOv];
#pragma unroll
        for (int i = 0; i < DOv; ++i) { xh0[i] = 0.f; xh1[i] = 0.f; }
#pragma unroll
        for (int r = 0; r < 128; ++r) {
            float wv = wlds[r][o ^ (r >> 2)];
            int i = r >> 3, j = r & 7;
            xh0[i] += wv * xa[j];
            xh1[i] += wv * xb[j];
        }

        float c0, c1;
        if (have_v) {
            float l0 = 0.f, l1 = 0.f;
#pragma unroll
            for (int i = 0; i < DOv; ++i) { l0 += xh0[i] * vc0[i]; l1 += xh1[i] * vc1[i]; }
            float m0 = l0, m1 = l1;
#pragma unroll
            for (int d = 16; d >= 1; d >>= 1) {
                m0 = fmaxf(m0, __shfl_xor(m0, d));
                m1 = fmaxf(m1, __shfl_xor(m1, d));
            }
            float e0 = __expf(l0 - m0), e1 = __expf(l1 - m1);
            float s0 = e0, s1 = e1;
#pragma unroll
            for (int d = 16; d >= 1; d >>= 1) {
                s0 += __shfl_xor(s0, d);
                s1 += __shfl_xor(s1, d);
            }
            c0 = e0 / s0; c1 = e1 / s1;
        } else {
            c0 = 1.0f / 32.0f; c1 = 1.0f / 32.0f;
        }

#pragma unroll
        for (int i = 0; i < DOv; ++i) { sacc0[i] += c0 * xh0[i]; sacc1[i] += c1 * xh1[i]; }
        __syncthreads();  // protect wlds before next stage
    }

    // plain stores of this chunk's partial (no atomics)
    float* p  = spart + (size_t)blockIdx.x * (Bb * Oo * DOv);
    float* p0 = p + ((size_t)(b0 + bl) * Oo + o) * DOv;
    float* p1 = p + ((size_t)(b0 + 8 + bl) * Oo + o) * DOv;
#pragma unroll
    for (int i = 0; i < DOv; ++i) p0[i] = sacc0[i];
#pragma unroll
    for (int i = 0; i < DOv; ++i) p1[i] = sacc1[i];
}

// Reduce nch partials, squash, update vcum and/or write output.
__global__ __launch_bounds__(512) void caps_squash(
    const float* __restrict__ spart, int nch,
    const float* __restrict__ vin,   // may be nullptr (treated as 0)
    float* __restrict__ vout,        // may be nullptr
    float* __restrict__ out)         // may be nullptr
{
    const int b = blockIdx.x;       // 0..63
    const int t = threadIdx.x;      // o*16 + i
    const size_t base = (size_t)b * (Oo * DOv) + t;
    float s = 0.f;
#pragma unroll 4
    for (int p = 0; p < nch; ++p)
        s += spart[(size_t)p * (Bb * Oo * DOv) + base];
    float n2 = s * s;
#pragma unroll
    for (int d = 8; d >= 1; d >>= 1) n2 += __shfl_xor(n2, d);  // reduce over Do=16
    float vj = s * (n2 / ((1.f + n2) * sqrtf(n2 + 1e-7f)));
    if (vout) vout[base] = (vin ? vin[base] : 0.f) + vj;
    if (out)  out[base] = vj;
}

extern "C" void kernel_launch(void* const* d_in, const int* in_sizes, int n_in,
                              void* d_out, int out_size, void* d_ws, size_t ws_size,
                              hipStream_t stream)
{
    const float* x = (const float*)d_in[0];
    const float* w = (const float*)d_in[1];
    float* out = (float*)d_out;

    // pick the largest n-split whose partial buffer fits the workspace
    static const int cfgs[][2] = {{72,16},{36,32},{18,64},{9,128},{4,288},{2,576},{1,1152}};
    int nch = 1, nc = 1152;
    for (auto& c : cfgs) {
        size_t need = ((size_t)c[0] * Bb * Oo * DOv + (size_t)Bb * Oo * DOv) * sizeof(float);
        if (need <= ws_size) { nch = c[0]; nc = c[1]; break; }
    }

    float* spart = (float*)d_ws;                               // [nch, B, O, DO]
    float* vcum  = spart + (size_t)nch * Bb * Oo * DOv;        // [B, O, DO]

    dim3 grid(nch, Bb / BPB);
    dim3 blk(256);
    dim3 sgrid(Bb), sblk(Oo * DOv);

    // iter 0: vcum = nullptr -> uniform c; squash overwrites vcum (no memset needed)
    caps_route<<<grid, blk, 0, stream>>>(x, w, nullptr, spart, nc);
    caps_squash<<<sgrid, sblk, 0, stream>>>(spart, nch, nullptr, vcum, nullptr);
    // iter 1
    caps_route<<<grid, blk, 0, stream>>>(x, w, vcum, spart, nc);
    caps_squash<<<sgrid, sblk, 0, stream>>>(spart, nch, vcum, vcum, nullptr);
    // iter 2
    caps_route<<<grid, blk, 0, stream>>>(x, w, vcum, spart, nc);
    caps_squash<<<sgrid, sblk, 0, stream>>>(spart, nch, nullptr, nullptr, out);
}

// Round 3
// 104.516 us; speedup vs baseline: 15.7442x; 1.3694x over previous
//
#include <hip/hip_runtime.h>

#define Bb 64
#define Nn 1152
#define Oo 32
#define DOv 16
#define DIv 8
#define BPB 16   // b's per block (2 groups of 8)

// async global->LDS, 16B per lane
__device__ __forceinline__ void gload_lds16(const void* g, void* l) {
    __builtin_amdgcn_global_load_lds(
        (const __attribute__((address_space(1))) unsigned*)g,
        (__attribute__((address_space(3))) unsigned*)l, 16, 0, 0);
}

// One routing iteration: recompute x_hat from (w, x), logits = <x_hat, vcum>,
// softmax over o, accumulate c * x_hat over this block's n-chunk, store partial s.
// vcum == nullptr -> uniform c = 1/32 (iteration 1).
__global__ __launch_bounds__(256) void caps_route(
    const float* __restrict__ x,     // [B, N, DI]
    const float* __restrict__ w,     // [N, O, DO, DI]
    const float* __restrict__ vcum,  // [B, O, DO] or nullptr
    float* __restrict__ spart,       // [nch, B, O, DO]
    int nc)
{
    const int t  = threadIdx.x;
    const int o  = t & 31;
    const int bl = t >> 5;            // 0..7
    const int n0 = blockIdx.x * nc;
    const int b0 = blockIdx.y * BPB;

    // wbuf phys float4 slot p holds global float4 (p&~31) | ((p^(p>>5))&31):
    // i.e. logical w[n][o][i2] lives at phys o*32 + (i2^o)  (XOR bank swizzle).
    // LDS dest of global_load_lds stays lane-linear; the GLOBAL index is pre-swizzled.
    __shared__ float4 wbuf[2][1024];      // 2 x 16 KB, double-buffered
    __shared__ float4 xbuf[16][BPB][2];   // x rows for up to 16 n's

    int gq[4];
#pragma unroll
    for (int k = 0; k < 4; ++k) {
        int p = k * 256 + t;
        gq[k] = (p & ~31) | ((p ^ (p >> 5)) & 31);
    }

    auto stageW = [&](int n, int c) {
        const float4* wg = (const float4*)(w + (size_t)n * (Oo * DOv * DIv));
#pragma unroll
        for (int k = 0; k < 4; ++k)
            gload_lds16(&wg[gq[k]], &wbuf[c][k * 256 + t]);
    };
    auto stageX = [&](int nb) {  // stage x for n0+nb .. n0+nb+15 (clamped)
        int cnt = min(16, nc - nb);
        for (int q = t; q < cnt * 32; q += 256) {
            int nn = q >> 5, bb = (q >> 1) & 15, h = q & 1;
            xbuf[nn][bb][h] = ((const float4*)(
                x + ((size_t)(b0 + bb) * Nn + (size_t)(n0 + nb + nn)) * DIv))[h];
        }
    };

    const bool have_v = (vcum != nullptr);
    float vc0[DOv], vc1[DOv];
    if (have_v) {
#pragma unroll
        for (int i = 0; i < DOv; ++i) vc0[i] = vcum[((size_t)(b0 + bl) * Oo + o) * DOv + i];
#pragma unroll
        for (int i = 0; i < DOv; ++i) vc1[i] = vcum[((size_t)(b0 + 8 + bl) * Oo + o) * DOv + i];
    }

    float sacc0[DOv], sacc1[DOv];
#pragma unroll
    for (int i = 0; i < DOv; ++i) { sacc0[i] = 0.f; sacc1[i] = 0.f; }

    stageX(0);
    stageW(n0, 0);
    int cur = 0;

    for (int nn = 0; nn < nc; ++nn) {
        if (nn && (nn & 15) == 0) { __syncthreads(); stageX(nn); }
        __syncthreads();                       // wbuf[cur] ready (vmcnt drained); xbuf visible
        if (nn + 1 < nc) stageW(n0 + nn + 1, cur ^ 1);  // fly under compute

        float4 xav0 = xbuf[nn & 15][bl][0],     xav1 = xbuf[nn & 15][bl][1];
        float4 xbv0 = xbuf[nn & 15][8 + bl][0], xbv1 = xbuf[nn & 15][8 + bl][1];
        float xa[8] = {xav0.x, xav0.y, xav0.z, xav0.w, xav1.x, xav1.y, xav1.z, xav1.w};
        float xb[8] = {xbv0.x, xbv0.y, xbv0.z, xbv0.w, xbv1.x, xbv1.y, xbv1.z, xbv1.w};

        float xh0[DOv], xh1[DOv];
#pragma unroll
        for (int i = 0; i < DOv; ++i) { xh0[i] = 0.f; xh1[i] = 0.f; }
#pragma unroll
        for (int i2 = 0; i2 < 32; ++i2) {
            float4 wv = wbuf[cur][o * 32 + (i2 ^ o)];  // = w[n][o][i2*4 .. +3]
            const int i = i2 >> 1, jb = (i2 & 1) * 4;
            xh0[i] = fmaf(wv.x, xa[jb + 0], xh0[i]);
            xh0[i] = fmaf(wv.y, xa[jb + 1], xh0[i]);
            xh0[i] = fmaf(wv.z, xa[jb + 2], xh0[i]);
            xh0[i] = fmaf(wv.w, xa[jb + 3], xh0[i]);
            xh1[i] = fmaf(wv.x, xb[jb + 0], xh1[i]);
            xh1[i] = fmaf(wv.y, xb[jb + 1], xh1[i]);
            xh1[i] = fmaf(wv.z, xb[jb + 2], xh1[i]);
            xh1[i] = fmaf(wv.w, xb[jb + 3], xh1[i]);
        }

        float c0, c1;
        if (have_v) {
            float l0 = 0.f, l1 = 0.f;
#pragma unroll
            for (int i = 0; i < DOv; ++i) { l0 += xh0[i] * vc0[i]; l1 += xh1[i] * vc1[i]; }
            float m0 = l0, m1 = l1;
#pragma unroll
            for (int d = 16; d >= 1; d >>= 1) {
                m0 = fmaxf(m0, __shfl_xor(m0, d));
                m1 = fmaxf(m1, __shfl_xor(m1, d));
            }
            float e0 = __expf(l0 - m0), e1 = __expf(l1 - m1);
            float s0 = e0, s1 = e1;
#pragma unroll
            for (int d = 16; d >= 1; d >>= 1) {
                s0 += __shfl_xor(s0, d);
                s1 += __shfl_xor(s1, d);
            }
            c0 = e0 / s0; c1 = e1 / s1;
        } else {
            c0 = 1.0f / 32.0f; c1 = 1.0f / 32.0f;
        }

#pragma unroll
        for (int i = 0; i < DOv; ++i) { sacc0[i] += c0 * xh0[i]; sacc1[i] += c1 * xh1[i]; }
        cur ^= 1;
    }

    float* p  = spart + (size_t)blockIdx.x * (Bb * Oo * DOv);
    float* p0 = p + ((size_t)(b0 + bl) * Oo + o) * DOv;
    float* p1 = p + ((size_t)(b0 + 8 + bl) * Oo + o) * DOv;
#pragma unroll
    for (int i = 0; i < DOv; ++i) p0[i] = sacc0[i];
#pragma unroll
    for (int i = 0; i < DOv; ++i) p1[i] = sacc1[i];
}

// Reduce nch partials + squash. One wave per (b, o). grid = (B, O).
__global__ __launch_bounds__(64) void caps_squash(
    const float* __restrict__ spart, int nch,
    const float* __restrict__ vin,   // may be nullptr (treated as 0)
    float* __restrict__ vout,        // may be nullptr
    float* __restrict__ out)         // may be nullptr
{
    const int b = blockIdx.x, oo = blockIdx.y;
    const int t = threadIdx.x;            // 0..63
    const int i = t & 15, pg = t >> 4;    // 4 p-groups
    const size_t base = ((size_t)b * Oo + oo) * DOv + i;
    float s = 0.f;
#pragma unroll 4
    for (int p = pg; p < nch; p += 4)
        s += spart[(size_t)p * (Bb * Oo * DOv) + base];
    s += __shfl_xor(s, 16);
    s += __shfl_xor(s, 32);               // all lanes: total s for their i
    float n2 = s * s;
#pragma unroll
    for (int d = 8; d >= 1; d >>= 1) n2 += __shfl_xor(n2, d);  // over Do=16
    float vj = s * (n2 / ((1.f + n2) * sqrtf(n2 + 1e-7f)));
    if (t < 16) {
        if (vout) vout[base] = (vin ? vin[base] : 0.f) + vj;
        if (out)  out[base]  = vj;
    }
}

extern "C" void kernel_launch(void* const* d_in, const int* in_sizes, int n_in,
                              void* d_out, int out_size, void* d_ws, size_t ws_size,
                              hipStream_t stream)
{
    const float* x = (const float*)d_in[0];
    const float* w = (const float*)d_in[1];
    float* out = (float*)d_out;

    // largest n-split whose partial buffer fits the workspace
    static const int cfgs[][2] = {{144,8},{72,16},{36,32},{18,64},{9,128},{4,288},{2,576},{1,1152}};
    int nch = 1, nc = 1152;
    for (auto& c : cfgs) {
        size_t need = ((size_t)c[0] * Bb * Oo * DOv + (size_t)Bb * Oo * DOv) * sizeof(float);
        if (need <= ws_size) { nch = c[0]; nc = c[1]; break; }
    }

    float* spart = (float*)d_ws;
    float* vcum  = spart + (size_t)nch * Bb * Oo * DOv;

    dim3 grid(nch, Bb / BPB), blk(256);
    dim3 sgrid(Bb, Oo), sblk(64);

    caps_route<<<grid, blk, 0, stream>>>(x, w, nullptr, spart, nc);
    caps_squash<<<sgrid, sblk, 0, stream>>>(spart, nch, nullptr, vcum, nullptr);
    caps_route<<<grid, blk, 0, stream>>>(x, w, vcum, spart, nc);
    caps_squash<<<sgrid, sblk, 0, stream>>>(spart, nch, vcum, vcum, nullptr);
    caps_route<<<grid, blk, 0, stream>>>(x, w, vcum, spart, nc);
    caps_squash<<<sgrid, sblk, 0, stream>>>(spart, nch, nullptr, nullptr, out);
}

// Round 4
// 103.722 us; speedup vs baseline: 15.8647x; 1.0077x over previous
//
#include <hip/hip_runtime.h>

#define Bb 64
#define Nn 1152
#define Oo 32
#define DOv 16
#define DIv 8
#define BPB 32   // b's per block (4 groups of 8 per thread)
#define NG 4     // b-groups per thread

// async global->LDS, 16B per lane
__device__ __forceinline__ void gload_lds16(const void* g, void* l) {
    __builtin_amdgcn_global_load_lds(
        (const __attribute__((address_space(1))) unsigned*)g,
        (__attribute__((address_space(3))) unsigned*)l, 16, 0, 0);
}

// One routing iteration: recompute x_hat from (w, x), logits = <x_hat, vcum>,
// softmax over o (no max-sub: |logit| < 1 by construction), accumulate
// c * x_hat over this block's n-chunk, store partial s.
// vcum == nullptr -> uniform c = 1/32 (iteration 1).
__global__ __launch_bounds__(256) void caps_route(
    const float* __restrict__ x,     // [B, N, DI]
    const float* __restrict__ w,     // [N, O, DO, DI]
    const float* __restrict__ vcum,  // [B, O, DO] or nullptr
    float* __restrict__ spart,       // [nch, B, O, DO]
    int nc)
{
    const int t  = threadIdx.x;
    const int o  = t & 31;
    const int bl = t >> 5;            // 0..7
    const int n0 = blockIdx.x * nc;
    const int b0 = blockIdx.y * BPB;

    // wbuf phys float4 slot p holds global float4 (p&~31) | ((p^(p>>5))&31):
    // logical w[n][o][i2] lives at phys o*32 + (i2^o)  (XOR bank swizzle).
    // LDS dest of global_load_lds stays lane-linear; GLOBAL index is pre-swizzled.
    __shared__ float4 wbuf[2][1024];      // 2 x 16 KB, double-buffered
    __shared__ float4 xbuf[16][BPB][2];   // x rows for up to 16 n's

    int gq[4];
#pragma unroll
    for (int k = 0; k < 4; ++k) {
        int p = k * 256 + t;
        gq[k] = (p & ~31) | ((p ^ (p >> 5)) & 31);
    }

    auto stageW = [&](int n, int c) {
        const float4* wg = (const float4*)(w + (size_t)n * (Oo * DOv * DIv));
#pragma unroll
        for (int k = 0; k < 4; ++k)
            gload_lds16(&wg[gq[k]], &wbuf[c][k * 256 + t]);
    };
    auto stageX = [&](int nb) {  // stage x for n0+nb .. n0+nb+15 (clamped)
        int cnt = min(16, nc - nb);
        for (int q = t; q < cnt * BPB * 2; q += 256) {
            int nn = q >> 6, bb = (q >> 1) & 31, h = q & 1;
            xbuf[nn][bb][h] = ((const float4*)(
                x + ((size_t)(b0 + bb) * Nn + (size_t)(n0 + nb + nn)) * DIv))[h];
        }
    };

    const bool have_v = (vcum != nullptr);
    float vc[NG][DOv];
    if (have_v) {
#pragma unroll
        for (int g = 0; g < NG; ++g)
#pragma unroll
            for (int i = 0; i < DOv; ++i)
                vc[g][i] = vcum[((size_t)(b0 + 8 * g + bl) * Oo + o) * DOv + i];
    }

    float sacc[NG][DOv];
#pragma unroll
    for (int g = 0; g < NG; ++g)
#pragma unroll
        for (int i = 0; i < DOv; ++i) sacc[g][i] = 0.f;

    stageX(0);
    stageW(n0, 0);
    int cur = 0;

    for (int nn = 0; nn < nc; ++nn) {
        if (nn && (nn & 15) == 0) { __syncthreads(); stageX(nn); }
        __syncthreads();                       // wbuf[cur] ready (vmcnt drained)
        if (nn + 1 < nc) stageW(n0 + nn + 1, cur ^ 1);  // fly under compute

        float xa[NG][DIv];
#pragma unroll
        for (int g = 0; g < NG; ++g) {
            float4 v0 = xbuf[nn & 15][8 * g + bl][0];
            float4 v1 = xbuf[nn & 15][8 * g + bl][1];
            xa[g][0] = v0.x; xa[g][1] = v0.y; xa[g][2] = v0.z; xa[g][3] = v0.w;
            xa[g][4] = v1.x; xa[g][5] = v1.y; xa[g][6] = v1.z; xa[g][7] = v1.w;
        }

        float xh[NG][DOv];
#pragma unroll
        for (int g = 0; g < NG; ++g)
#pragma unroll
            for (int i = 0; i < DOv; ++i) xh[g][i] = 0.f;

#pragma unroll
        for (int i2 = 0; i2 < 32; ++i2) {
            float4 wv = wbuf[cur][o * 32 + (i2 ^ o)];  // = w[n][o][i2*4 .. +3]
            const int i = i2 >> 1, jb = (i2 & 1) * 4;
#pragma unroll
            for (int g = 0; g < NG; ++g) {
                xh[g][i] = fmaf(wv.x, xa[g][jb + 0], xh[g][i]);
                xh[g][i] = fmaf(wv.y, xa[g][jb + 1], xh[g][i]);
                xh[g][i] = fmaf(wv.z, xa[g][jb + 2], xh[g][i]);
                xh[g][i] = fmaf(wv.w, xa[g][jb + 3], xh[g][i]);
            }
        }

        float c[NG];
        if (have_v) {
            float e[NG], ssum[NG];
#pragma unroll
            for (int g = 0; g < NG; ++g) {
                float l = 0.f;
#pragma unroll
                for (int i = 0; i < DOv; ++i) l += xh[g][i] * vc[g][i];
                e[g] = __expf(l);     // |l| < 1: no max-subtraction needed
                ssum[g] = e[g];
            }
#pragma unroll
            for (int d = 16; d >= 1; d >>= 1)
#pragma unroll
                for (int g = 0; g < NG; ++g)
                    ssum[g] += __shfl_xor(ssum[g], d);
#pragma unroll
            for (int g = 0; g < NG; ++g) c[g] = e[g] / ssum[g];
        } else {
#pragma unroll
            for (int g = 0; g < NG; ++g) c[g] = 1.0f / 32.0f;
        }

#pragma unroll
        for (int g = 0; g < NG; ++g)
#pragma unroll
            for (int i = 0; i < DOv; ++i) sacc[g][i] += c[g] * xh[g][i];
        cur ^= 1;
    }

    float* p = spart + (size_t)blockIdx.x * (Bb * Oo * DOv);
#pragma unroll
    for (int g = 0; g < NG; ++g) {
        float* pg = p + ((size_t)(b0 + 8 * g + bl) * Oo + o) * DOv;
#pragma unroll
        for (int i = 0; i < DOv; ++i) pg[i] = sacc[g][i];
    }
}

// Reduce nch partials + squash. One wave per (b, o). grid = (B, O).
__global__ __launch_bounds__(64) void caps_squash(
    const float* __restrict__ spart, int nch,
    const float* __restrict__ vin,   // may be nullptr (treated as 0)
    float* __restrict__ vout,        // may be nullptr
    float* __restrict__ out)         // may be nullptr
{
    const int b = blockIdx.x, oo = blockIdx.y;
    const int t = threadIdx.x;            // 0..63
    const int i = t & 15, pg = t >> 4;    // 4 p-groups
    const size_t base = ((size_t)b * Oo + oo) * DOv + i;
    float s = 0.f;
#pragma unroll 4
    for (int p = pg; p < nch; p += 4)
        s += spart[(size_t)p * (Bb * Oo * DOv) + base];
    s += __shfl_xor(s, 16);
    s += __shfl_xor(s, 32);               // all lanes: total s for their i
    float n2 = s * s;
#pragma unroll
    for (int d = 8; d >= 1; d >>= 1) n2 += __shfl_xor(n2, d);  // over Do=16
    float vj = s * (n2 / ((1.f + n2) * sqrtf(n2 + 1e-7f)));
    if (t < 16) {
        if (vout) vout[base] = (vin ? vin[base] : 0.f) + vj;
        if (out)  out[base]  = vj;
    }
}

extern "C" void kernel_launch(void* const* d_in, const int* in_sizes, int n_in,
                              void* d_out, int out_size, void* d_ws, size_t ws_size,
                              hipStream_t stream)
{
    const float* x = (const float*)d_in[0];
    const float* w = (const float*)d_in[1];
    float* out = (float*)d_out;

    // largest n-split whose partial buffer fits the workspace
    // primary: nch=128, nc=9 -> grid = 128 x 2 = 256 blocks = exactly 1/CU
    static const int cfgs[][2] = {{128,9},{72,16},{36,32},{18,64},{9,128},{4,288},{2,576},{1,1152}};
    int nch = 1, nc = 1152;
    for (auto& c : cfgs) {
        size_t need = ((size_t)c[0] * Bb * Oo * DOv + (size_t)Bb * Oo * DOv) * sizeof(float);
        if (need <= ws_size) { nch = c[0]; nc = c[1]; break; }
    }

    float* spart = (float*)d_ws;
    float* vcum  = spart + (size_t)nch * Bb * Oo * DOv;

    dim3 grid(nch, Bb / BPB), blk(256);
    dim3 sgrid(Bb, Oo), sblk(64);

    caps_route<<<grid, blk, 0, stream>>>(x, w, nullptr, spart, nc);
    caps_squash<<<sgrid, sblk, 0, stream>>>(spart, nch, nullptr, vcum, nullptr);
    caps_route<<<grid, blk, 0, stream>>>(x, w, vcum, spart, nc);
    caps_squash<<<sgrid, sblk, 0, stream>>>(spart, nch, vcum, vcum, nullptr);
    caps_route<<<grid, blk, 0, stream>>>(x, w, vcum, spart, nc);
    caps_squash<<<sgrid, sblk, 0, stream>>>(spart, nch, nullptr, nullptr, out);
}